// Round 1
// baseline (9031.926 us; speedup 1.0000x reference)
//
#include <hip/hip_runtime.h>
#include <math.h>

#define B_    16
#define N_    128
#define R_    16256
#define OBJD  64
#define RELD  32
#define EFFD  100
#define HID   150
#define NTILE 127            // R_ / 128

// ws layout (floats)
#define OW_OFF  0
#define OW_SIZE (B_ * N_ * 2 * HID)   // 614400 floats
#define EF_OFF  OW_SIZE
#define EF_SIZE (B_ * N_ * EFFD)      // 204800 floats

// ---------------- K0: fold objects @ rw1[0:128] into per-(b,n) weight rows ----------------
__global__ __launch_bounds__(192) void k0_ow(const float* __restrict__ obj,
                                             const float* __restrict__ rw1,
                                             float* __restrict__ ws) {
    const int bn = blockIdx.x;            // 0..2047  (b*128+n)
    const int j  = threadIdx.x;
    if (j >= HID) return;
    const float* o = obj + (size_t)bn * OBJD;
    float s = 0.f, rcv = 0.f;
#pragma unroll
    for (int d = 0; d < OBJD; ++d) {
        const float ov = o[d];                    // wave-uniform -> s_load
        s   += ov * rw1[d * HID + j];             // senders   part (rows 0..63)
        rcv += ov * rw1[(OBJD + d) * HID + j];    // receivers part (rows 64..127)
    }
    float* dst = ws + OW_OFF + (size_t)bn * (2 * HID);
    dst[j]       = s;
    dst[HID + j] = rcv;
}

// ---------------- K1: gather(folded) + 4-layer MLP + fused scatter ----------------
__global__ __launch_bounds__(128, 1) void k1_main(
    const float* __restrict__ SR, const float* __restrict__ RR,
    const float* __restrict__ REL,
    const float* __restrict__ rw1, const float* __restrict__ rb1,
    const float* __restrict__ rw2, const float* __restrict__ rb2,
    const float* __restrict__ rw3, const float* __restrict__ rb3,
    const float* __restrict__ rw4, const float* __restrict__ rb4,
    const float* __restrict__ ws, float* __restrict__ EF) {

    __shared__ float effs[128 * 104 + 32];   // [kk][104e] fp32, padded tail for te=7 overreads

    const int t    = threadIdx.x;            // relation within tile
    const int tile = blockIdx.x;             // 0..126
    const int b    = blockIdx.y;             // 0..15
    const int r    = tile * 128 + t;         // always < R_

    const float* SRp = SR + (size_t)b * N_ * R_ + r;
    const float* RRp = RR + (size_t)b * N_ * R_ + r;
    const float* ow  = ws + OW_OFF + (size_t)b * N_ * (2 * HID);

    float h1[HID], h2[HID];
#pragma unroll
    for (int j = 0; j < HID; ++j) h1[j] = rb1[j];

    // ---- phase A: folded gather (senders+receivers through rw1[0:128]) ----
    float sc = SRp[0], rc = RRp[0];
#pragma unroll 1
    for (int n = 0; n < N_; ++n) {
        float sn = 0.f, rn = 0.f;
        if (n + 1 < N_) {                     // prefetch next iteration's loads
            sn = SRp[(size_t)(n + 1) * R_];
            rn = RRp[(size_t)(n + 1) * R_];
        }
        const float* w = ow + n * (2 * HID);  // wave-uniform -> s_load stream
#pragma unroll
        for (int j = 0; j < HID; ++j) h1[j] += sc * w[j];
#pragma unroll
        for (int j = 0; j < HID; ++j) h1[j] += rc * w[HID + j];
        sc = sn; rc = rn;
    }
    // ---- rel_info part of layer 1 (rw1 rows 128..159) ----
    {
        const float* rp = REL + ((size_t)b * R_ + r) * RELD;
        float rv[RELD];
#pragma unroll
        for (int k = 0; k < RELD; k += 4) {
            const float4 v = *(const float4*)(rp + k);
            rv[k] = v.x; rv[k + 1] = v.y; rv[k + 2] = v.z; rv[k + 3] = v.w;
        }
#pragma unroll 1
        for (int k = 0; k < RELD; ++k) {
            const float a = rv[k];
            const float* w = rw1 + (2 * OBJD + k) * HID;
#pragma unroll
            for (int j = 0; j < HID; ++j) h1[j] += a * w[j];
        }
    }
    // ---- layer 2 ----
#pragma unroll
    for (int j = 0; j < HID; ++j) h2[j] = rb2[j];
#pragma unroll 1
    for (int k = 0; k < HID; ++k) {
        const float a = fmaxf(h1[k], 0.f);
        const float* w = rw2 + k * HID;
#pragma unroll
        for (int j = 0; j < HID; ++j) h2[j] += a * w[j];
    }
    // ---- layer 3 (into h1) ----
#pragma unroll
    for (int j = 0; j < HID; ++j) h1[j] = rb3[j];
#pragma unroll 1
    for (int k = 0; k < HID; ++k) {
        const float a = fmaxf(h2[k], 0.f);
        const float* w = rw3 + k * HID;
#pragma unroll
        for (int j = 0; j < HID; ++j) h1[j] += a * w[j];
    }
    // ---- layer 4 (into h2[0:100]) ----
#pragma unroll
    for (int e = 0; e < EFFD; ++e) h2[e] = rb4[e];
#pragma unroll 1
    for (int k = 0; k < HID; ++k) {
        const float a = fmaxf(h1[k], 0.f);
        const float* w = rw4 + k * EFFD;
#pragma unroll
        for (int e = 0; e < EFFD; ++e) h2[e] += a * w[e];
    }
    // ---- write relu(effects) for this relation into LDS row t ----
#pragma unroll
    for (int e = 0; e < EFFD; e += 4) {
        float4 v;
        v.x = fmaxf(h2[e], 0.f);     v.y = fmaxf(h2[e + 1], 0.f);
        v.z = fmaxf(h2[e + 2], 0.f); v.w = fmaxf(h2[e + 3], 0.f);
        *(float4*)&effs[t * 104 + e] = v;
    }
    __syncthreads();

    // ---- phase E: partial scatter  out[n][e] += sum_kk RR[b][n][r0+kk] * eff[kk][e] ----
    const int tn = t & 15, te = t >> 4;      // 16 x 8 thread grid
    const int n0 = tn * 8, e0 = te * 16;     // 8n x 16e register tile
    float acc[8][16];
#pragma unroll
    for (int i = 0; i < 8; ++i)
#pragma unroll
        for (int j = 0; j < 16; ++j) acc[i][j] = 0.f;

    const float* RRb = RR + (size_t)b * N_ * R_ + tile * 128;
#pragma unroll 1
    for (int kk = 0; kk < 128; kk += 8) {
        float rr[8][8];
#pragma unroll
        for (int i = 0; i < 8; ++i) {
            const float4 a = *(const float4*)(RRb + (size_t)(n0 + i) * R_ + kk);
            const float4 c = *(const float4*)(RRb + (size_t)(n0 + i) * R_ + kk + 4);
            rr[i][0] = a.x; rr[i][1] = a.y; rr[i][2] = a.z; rr[i][3] = a.w;
            rr[i][4] = c.x; rr[i][5] = c.y; rr[i][6] = c.z; rr[i][7] = c.w;
        }
#pragma unroll
        for (int q = 0; q < 8; ++q) {
            float ev[16];
#pragma unroll
            for (int j = 0; j < 16; j += 4) {
                const float4 v = *(const float4*)&effs[(kk + q) * 104 + e0 + j];
                ev[j] = v.x; ev[j + 1] = v.y; ev[j + 2] = v.z; ev[j + 3] = v.w;
            }
#pragma unroll
            for (int i = 0; i < 8; ++i)
#pragma unroll
                for (int j = 0; j < 16; ++j) acc[i][j] += rr[i][q] * ev[j];
        }
    }
    float* EFb = EF + (size_t)b * N_ * EFFD;
#pragma unroll
    for (int i = 0; i < 8; ++i)
#pragma unroll
        for (int j = 0; j < 16; ++j) {
            const int e = e0 + j;
            if (e < EFFD) atomicAdd(&EFb[(n0 + i) * EFFD + e], acc[i][j]);
        }
}

// ---------------- K3: object MLP + sigmoid ----------------
__global__ __launch_bounds__(128) void k3_out(
    const float* __restrict__ EF, const float* __restrict__ obj,
    const float* __restrict__ ow1, const float* __restrict__ ob1,
    const float* __restrict__ ow2, const float* __restrict__ ob2,
    float* __restrict__ out) {
    __shared__ float y[OBJD + EFFD];   // 164
    __shared__ float red[128];
    const int bn = blockIdx.x;         // 0..2047
    const int t  = threadIdx.x;
    if (t < OBJD) y[t] = obj[(size_t)bn * OBJD + t];
    if (t < EFFD) y[OBJD + t] = EF[(size_t)bn * EFFD + t];
    __syncthreads();
    float prod = 0.f;
    if (t < 100) {                     // OBJ_HID = 100
        float h = ob1[t];
#pragma unroll
        for (int k = 0; k < OBJD + EFFD; ++k) h += y[k] * ow1[k * 100 + t];
        prod = fmaxf(h, 0.f) * ow2[t];
    }
    red[t] = prod;
    __syncthreads();
#pragma unroll
    for (int s = 64; s > 0; s >>= 1) {
        if (t < s) red[t] += red[t + s];
        __syncthreads();
    }
    if (t == 0) {
        const float x = red[0] + ob2[0];
        float sig;
        if (x >= 0.f) sig = 1.f / (1.f + expf(-x));
        else { const float e = expf(x); sig = e / (1.f + e); }
        out[bn] = sig;
    }
}

extern "C" void kernel_launch(void* const* d_in, const int* in_sizes, int n_in,
                              void* d_out, int out_size, void* d_ws, size_t ws_size,
                              hipStream_t stream) {
    const float* obj = (const float*)d_in[0];
    const float* SR  = (const float*)d_in[1];
    const float* RR  = (const float*)d_in[2];
    const float* REL = (const float*)d_in[3];
    const float* rw1 = (const float*)d_in[4];
    const float* rb1 = (const float*)d_in[5];
    const float* rw2 = (const float*)d_in[6];
    const float* rb2 = (const float*)d_in[7];
    const float* rw3 = (const float*)d_in[8];
    const float* rb3 = (const float*)d_in[9];
    const float* rw4 = (const float*)d_in[10];
    const float* rb4 = (const float*)d_in[11];
    const float* ow1 = (const float*)d_in[12];
    const float* ob1 = (const float*)d_in[13];
    const float* ow2 = (const float*)d_in[14];
    const float* ob2 = (const float*)d_in[15];
    float* out = (float*)d_out;
    float* ws  = (float*)d_ws;
    float* EF  = ws + EF_OFF;

    // zero the scatter accumulator (ws is re-poisoned to 0xAA before every call)
    hipMemsetAsync(EF, 0, (size_t)EF_SIZE * sizeof(float), stream);

    k0_ow<<<dim3(B_ * N_), dim3(192), 0, stream>>>(obj, rw1, ws);
    k1_main<<<dim3(NTILE, B_), dim3(128), 0, stream>>>(SR, RR, REL, rw1, rb1, rw2, rb2,
                                                       rw3, rb3, rw4, rb4, ws, EF);
    k3_out<<<dim3(B_ * N_), dim3(128), 0, stream>>>(EF, obj, ow1, ob1, ow2, ob2, out);
}

// Round 2
// 5445.450 us; speedup vs baseline: 1.6586x; 1.6586x over previous
//
#include <hip/hip_runtime.h>
#include <math.h>

#define B_    16
#define N_    128
#define R_    16256
#define OBJD  64
#define RELD  32
#define EFFD  100
#define HID   150
#define NTILE 127            // R_ / 128
#define SROW  151            // LDS row stride in floats; odd -> <=2-way bank aliasing (free)

// ws layout (floats)
#define OW_OFF  0
#define OW_SIZE (B_ * N_ * 2 * HID)   // 614400 floats
#define EF_OFF  OW_SIZE
#define EF_SIZE (B_ * N_ * EFFD)      // 204800 floats

// ---------------- K0: fold objects @ rw1[0:128] into per-(b,n) weight rows ----------------
__global__ __launch_bounds__(192) void k0_ow(const float* __restrict__ obj,
                                             const float* __restrict__ rw1,
                                             float* __restrict__ ws) {
    const int bn = blockIdx.x;            // 0..2047  (b*128+n)
    const int j  = threadIdx.x;
    if (j >= HID) return;
    const float* o = obj + (size_t)bn * OBJD;
    float s = 0.f, rcv = 0.f;
#pragma unroll
    for (int d = 0; d < OBJD; ++d) {
        const float ov = o[d];                    // wave-uniform -> s_load
        s   += ov * rw1[d * HID + j];             // senders   part (rows 0..63)
        rcv += ov * rw1[(OBJD + d) * HID + j];    // receivers part (rows 64..127)
    }
    float* dst = ws + OW_OFF + (size_t)bn * (2 * HID);
    dst[j]       = s;
    dst[HID + j] = rcv;
}

// Generic MLP layer: reads relu(prev activations) from the thread's LDS row
// (runtime k index -> LDS, NOT a register array), accumulates into a register
// array with ONLY static indices, writes result back to the same LDS row.
template <int IN, int OUT, bool RELU_STORE>
__device__ __forceinline__ void mlp_layer(float* __restrict__ row,
                                          const float* __restrict__ W,
                                          const float* __restrict__ bias) {
    float h[OUT];
#pragma unroll
    for (int j = 0; j < OUT; ++j) h[j] = bias[j];
    float a = fmaxf(row[0], 0.f);
#pragma unroll 2
    for (int k = 0; k < IN; ++k) {
        const float an = (k + 1 < IN) ? row[k + 1] : 0.f;   // LDS prefetch next k
        const float* w = W + k * OUT;                        // wave-uniform -> s_load
#pragma unroll
        for (int j = 0; j < OUT; ++j) h[j] += a * w[j];
        a = fmaxf(an, 0.f);
    }
#pragma unroll
    for (int j = 0; j < OUT; ++j) row[j] = RELU_STORE ? fmaxf(h[j], 0.f) : h[j];
}

// ---------------- K1: gather(folded) + 4-layer MLP + fused scatter ----------------
__global__ __launch_bounds__(128, 1) void k1_main(
    const float* __restrict__ SR, const float* __restrict__ RR,
    const float* __restrict__ REL,
    const float* __restrict__ rw1, const float* __restrict__ rb1,
    const float* __restrict__ rw2, const float* __restrict__ rb2,
    const float* __restrict__ rw3, const float* __restrict__ rb3,
    const float* __restrict__ rw4, const float* __restrict__ rb4,
    const float* __restrict__ ws, float* __restrict__ EF) {

    __shared__ float lds[128 * SROW];        // per-thread activation row (75.5 KB)

    const int t    = threadIdx.x;            // relation within tile
    const int tile = blockIdx.x;             // 0..126
    const int b    = blockIdx.y;             // 0..15
    const int r    = tile * 128 + t;         // always < R_
    float* row = &lds[t * SROW];

    const float* SRp = SR + (size_t)b * N_ * R_ + r;
    const float* RRp = RR + (size_t)b * N_ * R_ + r;
    const float* ow  = ws + OW_OFF + (size_t)b * N_ * (2 * HID);

    float h[HID];
#pragma unroll
    for (int j = 0; j < HID; ++j) h[j] = rb1[j];

    // ---- phase A: folded gather (senders+receivers through rw1[0:128]) ----
    float sc = SRp[0], rc = RRp[0];
#pragma unroll 2
    for (int n = 0; n < N_; ++n) {
        float sn = 0.f, rn = 0.f;
        if (n + 1 < N_) {                     // prefetch next iteration's loads
            sn = SRp[(size_t)(n + 1) * R_];
            rn = RRp[(size_t)(n + 1) * R_];
        }
        const float* w = ow + n * (2 * HID);  // wave-uniform -> s_load stream
#pragma unroll
        for (int j = 0; j < HID; ++j) h[j] += sc * w[j];
#pragma unroll
        for (int j = 0; j < HID; ++j) h[j] += rc * w[HID + j];
        sc = sn; rc = rn;
    }

    // ---- rel_info part of layer 1 (rw1 rows 128..159): stage rel vec in LDS,
    //      runtime-k reads come from LDS (no register-array dynamic indexing) ----
    {
        const float* rp = REL + ((size_t)b * R_ + r) * RELD;
#pragma unroll
        for (int k = 0; k < RELD; k += 4) {
            const float4 v = *(const float4*)(rp + k);
            row[k] = v.x; row[k + 1] = v.y; row[k + 2] = v.z; row[k + 3] = v.w;
        }
        float a = row[0];
#pragma unroll 2
        for (int k = 0; k < RELD; ++k) {
            const float an = (k + 1 < RELD) ? row[k + 1] : 0.f;
            const float* w = rw1 + (2 * OBJD + k) * HID;
#pragma unroll
            for (int j = 0; j < HID; ++j) h[j] += a * w[j];
            a = an;
        }
    }
    // h1 (pre-relu) -> LDS row
#pragma unroll
    for (int j = 0; j < HID; ++j) row[j] = h[j];

    // ---- layers 2..4 (relu applied on read; layer 4 stores relu(effects)) ----
    mlp_layer<HID, HID, false>(row, rw2, rb2);
    mlp_layer<HID, HID, false>(row, rw3, rb3);
    mlp_layer<HID, EFFD, true>(row, rw4, rb4);

    __syncthreads();

    // ---- phase E: partial scatter  out[n][e] += sum_kk RR[b][n][r0+kk] * eff[kk][e] ----
    const int tn = t & 15, te = t >> 4;      // 16 x 8 thread grid
    const int n0 = tn * 8, e0 = te * 16;     // 8n x 16e register tile
    float acc[8][16];
#pragma unroll
    for (int i = 0; i < 8; ++i)
#pragma unroll
        for (int j = 0; j < 16; ++j) acc[i][j] = 0.f;

    const float* RRb = RR + (size_t)b * N_ * R_ + tile * 128;
#pragma unroll 1
    for (int kk = 0; kk < 128; kk += 8) {
        float rr[8][8];
#pragma unroll
        for (int i = 0; i < 8; ++i) {
            const float4 a = *(const float4*)(RRb + (size_t)(n0 + i) * R_ + kk);
            const float4 c = *(const float4*)(RRb + (size_t)(n0 + i) * R_ + kk + 4);
            rr[i][0] = a.x; rr[i][1] = a.y; rr[i][2] = a.z; rr[i][3] = a.w;
            rr[i][4] = c.x; rr[i][5] = c.y; rr[i][6] = c.z; rr[i][7] = c.w;
        }
#pragma unroll
        for (int q = 0; q < 8; ++q) {
            float ev[16];
#pragma unroll
            for (int j = 0; j < 16; ++j)
                ev[j] = lds[(kk + q) * SROW + e0 + j];   // rows e>=100 hold garbage; stores guarded
#pragma unroll
            for (int i = 0; i < 8; ++i)
#pragma unroll
                for (int j = 0; j < 16; ++j) acc[i][j] += rr[i][q] * ev[j];
        }
    }
    float* EFb = EF + (size_t)b * N_ * EFFD;
#pragma unroll
    for (int i = 0; i < 8; ++i)
#pragma unroll
        for (int j = 0; j < 16; ++j) {
            const int e = e0 + j;
            if (e < EFFD) atomicAdd(&EFb[(n0 + i) * EFFD + e], acc[i][j]);
        }
}

// ---------------- K3: object MLP + sigmoid ----------------
__global__ __launch_bounds__(128) void k3_out(
    const float* __restrict__ EF, const float* __restrict__ obj,
    const float* __restrict__ ow1, const float* __restrict__ ob1,
    const float* __restrict__ ow2, const float* __restrict__ ob2,
    float* __restrict__ out) {
    __shared__ float y[OBJD + EFFD];   // 164
    __shared__ float red[128];
    const int bn = blockIdx.x;         // 0..2047
    const int t  = threadIdx.x;
    if (t < OBJD) y[t] = obj[(size_t)bn * OBJD + t];
    if (t < EFFD) y[OBJD + t] = EF[(size_t)bn * EFFD + t];
    __syncthreads();
    float prod = 0.f;
    if (t < 100) {                     // OBJ_HID = 100
        float h = ob1[t];
#pragma unroll
        for (int k = 0; k < OBJD + EFFD; ++k) h += y[k] * ow1[k * 100 + t];
        prod = fmaxf(h, 0.f) * ow2[t];
    }
    red[t] = prod;
    __syncthreads();
#pragma unroll
    for (int s = 64; s > 0; s >>= 1) {
        if (t < s) red[t] += red[t + s];
        __syncthreads();
    }
    if (t == 0) {
        const float x = red[0] + ob2[0];
        float sig;
        if (x >= 0.f) sig = 1.f / (1.f + expf(-x));
        else { const float e = expf(x); sig = e / (1.f + e); }
        out[bn] = sig;
    }
}

extern "C" void kernel_launch(void* const* d_in, const int* in_sizes, int n_in,
                              void* d_out, int out_size, void* d_ws, size_t ws_size,
                              hipStream_t stream) {
    const float* obj = (const float*)d_in[0];
    const float* SR  = (const float*)d_in[1];
    const float* RR  = (const float*)d_in[2];
    const float* REL = (const float*)d_in[3];
    const float* rw1 = (const float*)d_in[4];
    const float* rb1 = (const float*)d_in[5];
    const float* rw2 = (const float*)d_in[6];
    const float* rb2 = (const float*)d_in[7];
    const float* rw3 = (const float*)d_in[8];
    const float* rb3 = (const float*)d_in[9];
    const float* rw4 = (const float*)d_in[10];
    const float* rb4 = (const float*)d_in[11];
    const float* ow1 = (const float*)d_in[12];
    const float* ob1 = (const float*)d_in[13];
    const float* ow2 = (const float*)d_in[14];
    const float* ob2 = (const float*)d_in[15];
    float* out = (float*)d_out;
    float* ws  = (float*)d_ws;
    float* EF  = ws + EF_OFF;

    // zero the scatter accumulator (ws is re-poisoned to 0xAA before every call)
    hipMemsetAsync(EF, 0, (size_t)EF_SIZE * sizeof(float), stream);

    k0_ow<<<dim3(B_ * N_), dim3(192), 0, stream>>>(obj, rw1, ws);
    k1_main<<<dim3(NTILE, B_), dim3(128), 0, stream>>>(SR, RR, REL, rw1, rb1, rw2, rb2,
                                                       rw3, rb3, rw4, rb4, ws, EF);
    k3_out<<<dim3(B_ * N_), dim3(128), 0, stream>>>(EF, obj, ow1, ob1, ow2, ob2, out);
}

// Round 3
// 1884.002 us; speedup vs baseline: 4.7940x; 2.8904x over previous
//
#include <hip/hip_runtime.h>
#include <math.h>

#define B_    16
#define N_    128
#define R_    16256
#define OBJD  64
#define RELD  32
#define EFFD  100
#define HID   150
#define MT    64             // relations per block
#define NTILE (R_ / MT)      // 254
#define KC    16             // K-chunk rows
#define WW    160            // Wbuf row width (padded out-dim)
#define SA    72             // Abuf row stride (64 + 8): epilogue writes <=2-way
#define SE    132            // EFF row stride (128 + 4): writes <=2-way

// ws layout (floats)
#define OW_OFF  0
#define OW_SIZE (B_ * N_ * 2 * HID)   // 614400 floats
#define EF_OFF  OW_SIZE
#define EF_SIZE (B_ * N_ * EFFD)      // 204800 floats

// ---------------- K0: fold objects @ rw1[0:128] into per-(b,n) weight rows ----------------
__global__ __launch_bounds__(192) void k0_ow(const float* __restrict__ obj,
                                             const float* __restrict__ rw1,
                                             float* __restrict__ ws) {
    const int bn = blockIdx.x;            // 0..2047  (b*128+n)
    const int j  = threadIdx.x;
    if (j >= HID) return;
    const float* o = obj + (size_t)bn * OBJD;
    float s = 0.f, rcv = 0.f;
#pragma unroll
    for (int d = 0; d < OBJD; ++d) {
        const float ov = o[d];
        s   += ov * rw1[d * HID + j];
        rcv += ov * rw1[(OBJD + d) * HID + j];
    }
    float* dst = ws + OW_OFF + (size_t)bn * (2 * HID);
    dst[j]       = s;
    dst[HID + j] = rcv;
}

// ---------------- K1: cooperative GEMM chain: gather -> MLP -> fused scatter ----------------
__global__ __launch_bounds__(256, 2) void k1_main(
    const float* __restrict__ SR, const float* __restrict__ RR,
    const float* __restrict__ REL,
    const float* __restrict__ rw1, const float* __restrict__ rb1,
    const float* __restrict__ rw2, const float* __restrict__ rb2,
    const float* __restrict__ rw3, const float* __restrict__ rb3,
    const float* __restrict__ rw4, const float* __restrict__ rb4,
    const float* __restrict__ ws, float* __restrict__ EF) {

    __shared__ float Abuf[160 * SA];        // activations [out][rel]; EFF overlay [rel][SE]
    __shared__ float Wbuf[2][KC * WW];      // weight K-chunk, double-buffered
    __shared__ float G1A[2][KC * MT];       // gather A-columns K-chunk, double-buffered

    const int t  = threadIdx.x;
    const int ti = t & 15;                  // rel-group (16)
    const int tj = t >> 4;                  // out-group (16)
    const int tile = blockIdx.x;            // 0..253
    const int b    = blockIdx.y;            // 0..15
    const int r0   = tile * MT;

    const float* ows = ws + OW_OFF + (size_t)b * N_ * (2 * HID);   // [n][300]

    // ---------- generic W-chunk staging: 2560 floats = 10/thread ----------
    auto w_store = [&](int bsel, const float* wr) {
#pragma unroll
        for (int q = 0; q < 10; ++q) Wbuf[bsel][t + 256 * q] = wr[q];
    };
    auto w_load_std = [&](const float* __restrict__ W, int cb, float* wr, int KLIM, int NLIM) {
#pragma unroll
        for (int q = 0; q < 10; ++q) {
            const int idx = t + 256 * q;
            const int row = idx / WW, col = idx - row * WW;
            const int k   = cb + row;
            wr[q] = (k < KLIM && col < NLIM) ? W[k * NLIM + col] : 0.f;
        }
    };

    // ================= G1: h1[64rel x 160] , K = 288 (128 SR + 128 RR + 32 REL) =================
    float acc[4][10];
#pragma unroll
    for (int j = 0; j < 10; ++j) {
        const int o = tj + 16 * j;
        const float bv = (o < HID) ? rb1[o] : 0.f;
#pragma unroll
        for (int i = 0; i < 4; ++i) acc[i][j] = bv;
    }

    auto g1_w_load = [&](int cb, float* wr) {
#pragma unroll
        for (int q = 0; q < 10; ++q) {
            const int idx = t + 256 * q;
            const int row = idx / WW, col = idx - row * WW;
            const int k   = cb + row;
            float v = 0.f;
            if (col < HID) {
                if (k < 128)      v = ows[k * 300 + col];
                else if (k < 256) v = ows[(k - 128) * 300 + HID + col];
                else              v = rw1[(128 + (k - 256)) * HID + col];
            }
            wr[q] = v;
        }
    };
    auto g1_a_load = [&](int cb, float4* ar) {
        if (cb < 256) {
            const float* src = (cb < 128) ? SR : RR;
            const int n = (cb < 128 ? cb : cb - 128) + tj;          // 16 cols/chunk
            *ar = *(const float4*)(src + (size_t)(b * N_ + n) * R_ + r0 + ti * 4);
        } else {
            const int rr = t & 63, kk = (t >> 6) * 4;               // REL transposed
            *ar = *(const float4*)(REL + ((size_t)b * R_ + r0 + rr) * RELD + (cb - 256) + kk);
        }
    };
    auto g1_a_store = [&](int cb, int bsel, float4 ar) {
        if (cb < 256) {
            *(float4*)&G1A[bsel][tj * MT + ti * 4] = ar;
        } else {
            const int rr = t & 63, kk = (t >> 6) * 4;
            G1A[bsel][(kk + 0) * MT + rr] = ar.x;
            G1A[bsel][(kk + 1) * MT + rr] = ar.y;
            G1A[bsel][(kk + 2) * MT + rr] = ar.z;
            G1A[bsel][(kk + 3) * MT + rr] = ar.w;
        }
    };

    {
        float wr[10]; float4 ar;
        g1_w_load(0, wr); g1_a_load(0, &ar);
        w_store(0, wr);   g1_a_store(0, 0, ar);
        __syncthreads();
        for (int c = 0; c < 18; ++c) {
            const int nb = (c + 1) & 1;
            if (c + 1 < 18) { g1_w_load((c + 1) * KC, wr); g1_a_load((c + 1) * KC, &ar); }
#pragma unroll
            for (int k = 0; k < KC; ++k) {
                float a[4], w[10];
#pragma unroll
                for (int i = 0; i < 4; ++i) a[i] = G1A[c & 1][k * MT + ti + 16 * i];
#pragma unroll
                for (int j = 0; j < 10; ++j) w[j] = Wbuf[c & 1][k * WW + tj + 16 * j];
#pragma unroll
                for (int i = 0; i < 4; ++i)
#pragma unroll
                    for (int j = 0; j < 10; ++j) acc[i][j] = fmaf(a[i], w[j], acc[i][j]);
            }
            if (c + 1 < 18) { w_store(nb, wr); g1_a_store((c + 1) * KC, nb, ar); }
            __syncthreads();
        }
    }
    // epilogue: relu -> Abuf[out][rel]
#pragma unroll
    for (int j = 0; j < 10; ++j)
#pragma unroll
        for (int i = 0; i < 4; ++i)
            Abuf[(tj + 16 * j) * SA + ti + 16 * i] = fmaxf(acc[i][j], 0.f);
    __syncthreads();

    // ================= G2, G3: [64 x 160] @ W[160 x 160], K padded to 160 =================
    const float* Ws[2] = {rw2, rw3};
    const float* Bs[2] = {rb2, rb3};
    for (int L = 0; L < 2; ++L) {
        const float* W = Ws[L];
        const float* bias = Bs[L];
        float acc2[4][10];
#pragma unroll
        for (int j = 0; j < 10; ++j) {
            const int o = tj + 16 * j;
            const float bv = (o < HID) ? bias[o] : 0.f;
#pragma unroll
            for (int i = 0; i < 4; ++i) acc2[i][j] = bv;
        }
        float wr[10];
        w_load_std(W, 0, wr, HID, HID);
        w_store(0, wr);
        __syncthreads();
        for (int c = 0; c < 10; ++c) {
            if (c + 1 < 10) w_load_std(W, (c + 1) * KC, wr, HID, HID);
#pragma unroll
            for (int k = 0; k < KC; ++k) {
                const int kg = c * KC + k;
                float a[4], w[10];
#pragma unroll
                for (int i = 0; i < 4; ++i) a[i] = Abuf[kg * SA + ti + 16 * i];
#pragma unroll
                for (int j = 0; j < 10; ++j) w[j] = Wbuf[c & 1][k * WW + tj + 16 * j];
#pragma unroll
                for (int i = 0; i < 4; ++i)
#pragma unroll
                    for (int j = 0; j < 10; ++j) acc2[i][j] = fmaf(a[i], w[j], acc2[i][j]);
            }
            if (c + 1 < 10) w_store((c + 1) & 1, wr);
            __syncthreads();
        }
#pragma unroll
        for (int j = 0; j < 10; ++j)
#pragma unroll
            for (int i = 0; i < 4; ++i)
                Abuf[(tj + 16 * j) * SA + ti + 16 * i] = fmaxf(acc2[i][j], 0.f);
        __syncthreads();
    }

    // ================= G4: effects [64 x 128(pad of 100)] =================
    {
        float acc4[4][8];
#pragma unroll
        for (int j = 0; j < 8; ++j) {
            const int o = tj + 16 * j;
            const float bv = (o < EFFD) ? rb4[o] : 0.f;
#pragma unroll
            for (int i = 0; i < 4; ++i) acc4[i][j] = bv;
        }
        float wr[10];
        w_load_std(rw4, 0, wr, HID, EFFD);
        w_store(0, wr);
        __syncthreads();
        for (int c = 0; c < 10; ++c) {
            if (c + 1 < 10) w_load_std(rw4, (c + 1) * KC, wr, HID, EFFD);
#pragma unroll
            for (int k = 0; k < KC; ++k) {
                const int kg = c * KC + k;
                float a[4], w[8];
#pragma unroll
                for (int i = 0; i < 4; ++i) a[i] = Abuf[kg * SA + ti + 16 * i];
#pragma unroll
                for (int j = 0; j < 8; ++j) w[j] = Wbuf[c & 1][k * WW + tj + 16 * j];
#pragma unroll
                for (int i = 0; i < 4; ++i)
#pragma unroll
                    for (int j = 0; j < 8; ++j) acc4[i][j] = fmaf(a[i], w[j], acc4[i][j]);
            }
            if (c + 1 < 10) w_store((c + 1) & 1, wr);
            __syncthreads();
        }
        // relu -> EFF overlay [rel][e], stride SE (all 160 A-rows consumed; barrier passed)
#pragma unroll
        for (int j = 0; j < 8; ++j)
#pragma unroll
            for (int i = 0; i < 4; ++i)
                Abuf[(ti + 16 * i) * SE + tj + 16 * j] = fmaxf(acc4[i][j], 0.f);
        __syncthreads();
    }

    // ================= Phase E: EF[n][e] += sum_r RR[n][r0+r] * eff[r][e] =================
    {
        float accE[8][8];
#pragma unroll
        for (int i = 0; i < 8; ++i)
#pragma unroll
            for (int j = 0; j < 8; ++j) accE[i][j] = 0.f;

        const float* RRt = RR + (size_t)b * N_ * R_ + r0;
        for (int k4 = 0; k4 < MT; k4 += 4) {
            // first half: n-rows i=0..3
            float4 ra[4];
#pragma unroll
            for (int i = 0; i < 4; ++i)
                ra[i] = *(const float4*)(RRt + (size_t)(ti + 16 * i) * R_ + k4);
#pragma unroll
            for (int q = 0; q < 4; ++q) {
                float ev[8];
#pragma unroll
                for (int j = 0; j < 8; ++j) ev[j] = Abuf[(k4 + q) * SE + tj + 16 * j];
#pragma unroll
                for (int i = 0; i < 4; ++i) {
                    const float av = (q == 0) ? ra[i].x : (q == 1) ? ra[i].y : (q == 2) ? ra[i].z : ra[i].w;
#pragma unroll
                    for (int j = 0; j < 8; ++j) accE[i][j] = fmaf(av, ev[j], accE[i][j]);
                }
            }
            // second half: n-rows i=4..7
#pragma unroll
            for (int i = 0; i < 4; ++i)
                ra[i] = *(const float4*)(RRt + (size_t)(ti + 16 * (i + 4)) * R_ + k4);
#pragma unroll
            for (int q = 0; q < 4; ++q) {
                float ev[8];
#pragma unroll
                for (int j = 0; j < 8; ++j) ev[j] = Abuf[(k4 + q) * SE + tj + 16 * j];
#pragma unroll
                for (int i = 0; i < 4; ++i) {
                    const float av = (q == 0) ? ra[i].x : (q == 1) ? ra[i].y : (q == 2) ? ra[i].z : ra[i].w;
#pragma unroll
                    for (int j = 0; j < 8; ++j) accE[i + 4][j] = fmaf(av, ev[j], accE[i + 4][j]);
                }
            }
        }
        float* EFb = EF + (size_t)b * N_ * EFFD;
#pragma unroll
        for (int i = 0; i < 8; ++i)
#pragma unroll
            for (int j = 0; j < 8; ++j) {
                const int e = tj + 16 * j;
                if (e < EFFD) atomicAdd(&EFb[(ti + 16 * i) * EFFD + e], accE[i][j]);
            }
    }
}

// ---------------- K3: object MLP + sigmoid ----------------
__global__ __launch_bounds__(128) void k3_out(
    const float* __restrict__ EF, const float* __restrict__ obj,
    const float* __restrict__ ow1, const float* __restrict__ ob1,
    const float* __restrict__ ow2, const float* __restrict__ ob2,
    float* __restrict__ out) {
    __shared__ float y[OBJD + EFFD];   // 164
    __shared__ float red[128];
    const int bn = blockIdx.x;         // 0..2047
    const int t  = threadIdx.x;
    if (t < OBJD) y[t] = obj[(size_t)bn * OBJD + t];
    if (t < EFFD) y[OBJD + t] = EF[(size_t)bn * EFFD + t];
    __syncthreads();
    float prod = 0.f;
    if (t < 100) {                     // OBJ_HID = 100
        float h = ob1[t];
#pragma unroll
        for (int k = 0; k < OBJD + EFFD; ++k) h += y[k] * ow1[k * 100 + t];
        prod = fmaxf(h, 0.f) * ow2[t];
    }
    red[t] = prod;
    __syncthreads();
#pragma unroll
    for (int s = 64; s > 0; s >>= 1) {
        if (t < s) red[t] += red[t + s];
        __syncthreads();
    }
    if (t == 0) {
        const float x = red[0] + ob2[0];
        float sig;
        if (x >= 0.f) sig = 1.f / (1.f + expf(-x));
        else { const float e = expf(x); sig = e / (1.f + e); }
        out[bn] = sig;
    }
}

extern "C" void kernel_launch(void* const* d_in, const int* in_sizes, int n_in,
                              void* d_out, int out_size, void* d_ws, size_t ws_size,
                              hipStream_t stream) {
    const float* obj = (const float*)d_in[0];
    const float* SR  = (const float*)d_in[1];
    const float* RR  = (const float*)d_in[2];
    const float* REL = (const float*)d_in[3];
    const float* rw1 = (const float*)d_in[4];
    const float* rb1 = (const float*)d_in[5];
    const float* rw2 = (const float*)d_in[6];
    const float* rb2 = (const float*)d_in[7];
    const float* rw3 = (const float*)d_in[8];
    const float* rb3 = (const float*)d_in[9];
    const float* rw4 = (const float*)d_in[10];
    const float* rb4 = (const float*)d_in[11];
    const float* ow1 = (const float*)d_in[12];
    const float* ob1 = (const float*)d_in[13];
    const float* ow2 = (const float*)d_in[14];
    const float* ob2 = (const float*)d_in[15];
    float* out = (float*)d_out;
    float* ws  = (float*)d_ws;
    float* EF  = ws + EF_OFF;

    hipMemsetAsync(EF, 0, (size_t)EF_SIZE * sizeof(float), stream);

    k0_ow<<<dim3(B_ * N_), dim3(192), 0, stream>>>(obj, rw1, ws);
    k1_main<<<dim3(NTILE, B_), dim3(256), 0, stream>>>(SR, RR, REL, rw1, rb1, rw2, rb2,
                                                       rw3, rb3, rw4, rb4, ws, EF);
    k3_out<<<dim3(B_ * N_), dim3(128), 0, stream>>>(EF, obj, ow1, ob1, ow2, ob2, out);
}